// Round 19
// baseline (497.101 us; speedup 1.0000x reference)
//
#include <hip/hip_runtime.h>

#define EDIM 128
#define NE   1024
#define TAU  5e-5f   // disagreement bound 3.36e-5 (2*ulp(128)+split err) x1.49 margin
#define CAPP 65536   // pair-list capacity (entries); overflow -> full list

typedef short v8s __attribute__((ext_vector_type(8)));
typedef float v4f __attribute__((ext_vector_type(4)));
typedef __attribute__((address_space(3))) void       lds_t;
typedef const __attribute__((address_space(1))) void gm_t;

__device__ inline unsigned bf16_rne(float f) {
    unsigned u = __float_as_uint(f);
    return (u + 0x7fffu + ((u >> 16) & 1u)) >> 16;
}
__device__ inline float bf16_tof(unsigned h) { return __uint_as_float(h << 16); }

// ---- prep: W -> fragment-ordered bf16 hi/lo via LDS bounce, W -> Wt, swsq ----
// Fragment order (shorts): o = sub*2048 + ks*512 + g*128 + m*8 + e for
// code = sub*16+m, k = ks*32+g*8+e  (identical layout to r15-r18).
__global__ void vq_prep(const float* __restrict__ W,
                        unsigned short* __restrict__ whiF,
                        unsigned short* __restrict__ wloF,
                        float* __restrict__ Wt,
                        float* __restrict__ swsq_ws)
{
#pragma clang fp contract(off)
    __shared__ unsigned short lh[2048], ll[2048];   // 8 KB bounce
    const int tid = threadIdx.x;
    const int t = blockIdx.x * 256 + tid;           // 256 blocks

    if (blockIdx.x < 64) {   // fragment reorder: one 16-code subtile per block
        const int sub = blockIdx.x;
        const int dst = ((tid & 15) >> 2) * 512 + (tid & 3) * 128 + (tid >> 4) * 8;
        float4 p0 = reinterpret_cast<const float4*>(W)[sub * 512 + tid * 2];
        float4 p1 = reinterpret_cast<const float4*>(W)[sub * 512 + tid * 2 + 1];
        float v[8] = {p0.x,p0.y,p0.z,p0.w,p1.x,p1.y,p1.z,p1.w};
        v8s hh, llw;
        #pragma unroll
        for (int j = 0; j < 8; ++j) {
            unsigned h = bf16_rne(v[j]);
            hh[j]  = (short)h;
            llw[j] = (short)bf16_rne(v[j] - bf16_tof(h));
        }
        *reinterpret_cast<v8s*>(&lh[dst]) = hh;
        *reinterpret_cast<v8s*>(&ll[dst]) = llw;
        __syncthreads();
        *reinterpret_cast<v8s*>(&whiF[sub * 2048 + tid * 8]) =
            *reinterpret_cast<const v8s*>(&lh[tid * 8]);
        *reinterpret_cast<v8s*>(&wloF[sub * 2048 + tid * 8]) =
            *reinterpret_cast<const v8s*>(&ll[tid * 8]);
    }

    #pragma unroll
    for (int rep = 0; rep < 2; ++rep) {
        int o2 = t + rep * 65536;
        Wt[o2] = W[(o2 & 1023) * EDIM + (o2 >> 10)];   // coalesced write
    }

    if (t < NE) {   // numpy pairwise 8-acc pattern (validated rounds 2-18)
        const float4* wr = reinterpret_cast<const float4*>(W) + (size_t)t * 32;
        float4 A = wr[0], B = wr[1];
        float r0 = A.x*A.x, r1 = A.y*A.y, r2 = A.z*A.z, r3 = A.w*A.w;
        float r4 = B.x*B.x, r5 = B.y*B.y, r6 = B.z*B.z, r7 = B.w*B.w;
        #pragma unroll
        for (int i = 2; i < 32; i += 2) {
            float4 C = wr[i], D = wr[i + 1];
            r0 += C.x*C.x; r1 += C.y*C.y; r2 += C.z*C.z; r3 += C.w*C.w;
            r4 += D.x*D.x; r5 += D.y*D.y; r6 += D.z*D.z; r7 += D.w*D.w;
        }
        swsq_ws[t] = ((r0 + r1) + (r2 + r3)) + ((r4 + r5) + (r6 + r7));
    }
}

union SMem {
    struct { unsigned short ring[3][2][2048]; float snwk2h[NE]; } p1;   // 28672 B
    struct { float2 sbs[2048]; int sbk[2048]; int sbest[128]; } p2;     // 25088 B
};

// ---- stage 1: 16-code tiles, 3-ring counted-vmcnt, 28.7KB LDS -> 5 blocks/CU ----
__global__ __launch_bounds__(256, 4) void vq_mfma12(
    const float* __restrict__ x,
    const unsigned short* __restrict__ whiF, const unsigned short* __restrict__ wloF,
    const float* __restrict__ W, const float* __restrict__ swsq_ws,
    float* __restrict__ zq, float* __restrict__ idxout,
    int* __restrict__ cnt_pair, int* __restrict__ cnt_full,
    int* __restrict__ plist, int* __restrict__ flist)
{
    __shared__ SMem sm;

    const int tid = threadIdx.x;
    const int wid = tid >> 6;
    const int l   = tid & 63;
    const int m   = l & 15;          // B-code / C-col
    const int g   = l >> 4;          // k-group; C rows g*4+r

    const long long row0 = (long long)blockIdx.x * 128;
    const float4* x4 = reinterpret_cast<const float4*>(x);
    const float4* W4 = reinterpret_cast<const float4*>(W);

#define STAGE_TILE(T, B) do {                                                          \
    __builtin_amdgcn_global_load_lds((gm_t*)(whiF + (size_t)(T) * 2048 + tid * 8),     \
        (lds_t*)&sm.p1.ring[B][0][tid * 8], 16, 0, 0);                                 \
    __builtin_amdgcn_global_load_lds((gm_t*)(wloF + (size_t)(T) * 2048 + tid * 8),     \
        (lds_t*)&sm.p1.ring[B][1][tid * 8], 16, 0, 0);                                 \
} while (0)

    // prologue: issue tiles 0,1
    STAGE_TILE(0, 0);
    STAGE_TILE(1, 1);

    {   // stage -wk2/2 into LDS
        float4 v = reinterpret_cast<const float4*>(swsq_ws)[tid];
        v.x *= -0.5f; v.y *= -0.5f; v.z *= -0.5f; v.w *= -0.5f;
        reinterpret_cast<float4*>(sm.p1.snwk2h)[tid] = v;
    }

    // A-fragments for 2 row-subtiles: rows row0+wid*32+m and +16
    const long long rA0 = row0 + wid * 32 + m;
    const long long rA1 = rA0 + 16;
    v8s a0h[4], a0l[4], a1h[4], a1l[4];
    #pragma unroll
    for (int ks = 0; ks < 4; ++ks) {
        float4 p0 = x4[rA0 * 32 + ks * 8 + g * 2];
        float4 p1 = x4[rA0 * 32 + ks * 8 + g * 2 + 1];
        float4 q0 = x4[rA1 * 32 + ks * 8 + g * 2];
        float4 q1 = x4[rA1 * 32 + ks * 8 + g * 2 + 1];
        float vp[8] = {p0.x,p0.y,p0.z,p0.w,p1.x,p1.y,p1.z,p1.w};
        float vq[8] = {q0.x,q0.y,q0.z,q0.w,q1.x,q1.y,q1.z,q1.w};
        #pragma unroll
        for (int e = 0; e < 8; ++e) {
            unsigned h0 = bf16_rne(vp[e]);
            a0h[ks][e] = (short)h0;
            a0l[ks][e] = (short)bf16_rne(vp[e] - bf16_tof(h0));
            unsigned h1 = bf16_rne(vq[e]);
            a1h[ks][e] = (short)h1;
            a1l[ks][e] = (short)bf16_rne(vq[e] - bf16_tof(h1));
        }
    }
    __syncthreads();   // drains prologue staging (tiles 0,1) + snwk2h

    float best[8], sec[8]; int bk[8];
    #pragma unroll
    for (int r = 0; r < 8; ++r) { best[r] = -3.4e38f; sec[r] = -3.4e38f; bk[r] = 0; }

    int bcur = 0;                       // t % 3
    #pragma unroll 1
    for (int t = 0; t < 64; ++t) {
        // counted wait: tile t's 2 loads landed; tile t+1's 2 stay in flight
        if (t + 1 < 64) asm volatile("s_waitcnt vmcnt(2)" ::: "memory");
        else            asm volatile("s_waitcnt vmcnt(0)" ::: "memory");
        __builtin_amdgcn_s_barrier();

        if (t + 2 < 64) {
            int bnext = bcur + 2; if (bnext >= 3) bnext -= 3;
            STAGE_TILE(t + 2, bnext);
        }

        const unsigned short* bh_base = &sm.p1.ring[bcur][0][l * 8];
        const unsigned short* bl_base = &sm.p1.ring[bcur][1][l * 8];
        v8s bh0 = *(const v8s*)(bh_base);
        v8s bh1 = *(const v8s*)(bh_base + 512);
        v8s bh2 = *(const v8s*)(bh_base + 1024);
        v8s bh3 = *(const v8s*)(bh_base + 1536);
        v8s bl0 = *(const v8s*)(bl_base);
        v8s bl1 = *(const v8s*)(bl_base + 512);
        v8s bl2 = *(const v8s*)(bl_base + 1024);
        v8s bl3 = *(const v8s*)(bl_base + 1536);

        const int k = t * 16 + m;
        const float h = sm.p1.snwk2h[k];     // -wk2/2, C-init (broadcast)
        v4f acc0 = {h, h, h, h};
        v4f acc1 = {h, h, h, h};
        __builtin_amdgcn_s_setprio(1);
        acc0 = __builtin_amdgcn_mfma_f32_16x16x32_bf16(a0h[0], bh0, acc0, 0, 0, 0);
        acc0 = __builtin_amdgcn_mfma_f32_16x16x32_bf16(a0l[0], bh0, acc0, 0, 0, 0);
        acc0 = __builtin_amdgcn_mfma_f32_16x16x32_bf16(a0h[0], bl0, acc0, 0, 0, 0);
        acc1 = __builtin_amdgcn_mfma_f32_16x16x32_bf16(a1h[0], bh0, acc1, 0, 0, 0);
        acc1 = __builtin_amdgcn_mfma_f32_16x16x32_bf16(a1l[0], bh0, acc1, 0, 0, 0);
        acc1 = __builtin_amdgcn_mfma_f32_16x16x32_bf16(a1h[0], bl0, acc1, 0, 0, 0);
        acc0 = __builtin_amdgcn_mfma_f32_16x16x32_bf16(a0h[1], bh1, acc0, 0, 0, 0);
        acc0 = __builtin_amdgcn_mfma_f32_16x16x32_bf16(a0l[1], bh1, acc0, 0, 0, 0);
        acc0 = __builtin_amdgcn_mfma_f32_16x16x32_bf16(a0h[1], bl1, acc0, 0, 0, 0);
        acc1 = __builtin_amdgcn_mfma_f32_16x16x32_bf16(a1h[1], bh1, acc1, 0, 0, 0);
        acc1 = __builtin_amdgcn_mfma_f32_16x16x32_bf16(a1l[1], bh1, acc1, 0, 0, 0);
        acc1 = __builtin_amdgcn_mfma_f32_16x16x32_bf16(a1h[1], bl1, acc1, 0, 0, 0);
        acc0 = __builtin_amdgcn_mfma_f32_16x16x32_bf16(a0h[2], bh2, acc0, 0, 0, 0);
        acc0 = __builtin_amdgcn_mfma_f32_16x16x32_bf16(a0l[2], bh2, acc0, 0, 0, 0);
        acc0 = __builtin_amdgcn_mfma_f32_16x16x32_bf16(a0h[2], bl2, acc0, 0, 0, 0);
        acc1 = __builtin_amdgcn_mfma_f32_16x16x32_bf16(a1h[2], bh2, acc1, 0, 0, 0);
        acc1 = __builtin_amdgcn_mfma_f32_16x16x32_bf16(a1l[2], bh2, acc1, 0, 0, 0);
        acc1 = __builtin_amdgcn_mfma_f32_16x16x32_bf16(a1h[2], bl2, acc1, 0, 0, 0);
        acc0 = __builtin_amdgcn_mfma_f32_16x16x32_bf16(a0h[3], bh3, acc0, 0, 0, 0);
        acc0 = __builtin_amdgcn_mfma_f32_16x16x32_bf16(a0l[3], bh3, acc0, 0, 0, 0);
        acc0 = __builtin_amdgcn_mfma_f32_16x16x32_bf16(a0h[3], bl3, acc0, 0, 0, 0);
        acc1 = __builtin_amdgcn_mfma_f32_16x16x32_bf16(a1h[3], bh3, acc1, 0, 0, 0);
        acc1 = __builtin_amdgcn_mfma_f32_16x16x32_bf16(a1l[3], bh3, acc1, 0, 0, 0);
        acc1 = __builtin_amdgcn_mfma_f32_16x16x32_bf16(a1h[3], bl3, acc1, 0, 0, 0);
        __builtin_amdgcn_s_setprio(0);

        #pragma unroll
        for (int r = 0; r < 4; ++r) {
            float b0 = best[r];
            float a0r = acc0[r];
            sec[r]  = __builtin_amdgcn_fmed3f(a0r, b0, sec[r]);   // 2nd-largest
            bk[r]   = (a0r > b0) ? k : bk[r];
            best[r] = fmaxf(b0, a0r);
            float b1 = best[4 + r];
            float a1r = acc1[r];
            sec[4+r]  = __builtin_amdgcn_fmed3f(a1r, b1, sec[4+r]);
            bk[4+r]   = (a1r > b1) ? k : bk[4+r];
            best[4+r] = fmaxf(b1, a1r);
        }

        bcur = (bcur == 2) ? 0 : bcur + 1;
    }
    __syncthreads();   // ring reads done before scan overwrites (union)

    // ---- dump per-lane top-2 (converted back to s = -2a) + census ----
    #pragma unroll
    for (int r = 0; r < 8; ++r) {
        int rowL = wid * 32 + ((r >> 2) << 4) + (g << 2) + (r & 3);
        float2 e; e.x = -2.f * best[r]; e.y = -2.f * sec[r];
        sm.p2.sbs[rowL * 16 + m] = e;
        sm.p2.sbk[rowL * 16 + m] = bk[r];
    }
    __syncthreads();

    if (tid < 128) {
        const int stag = tid & 7;                 // slot stagger (order-independent)
        float b1 = 3.4e38f; int k1 = 0x7fffffff;
        #pragma unroll 1
        for (int mm = 0; mm < 16; ++mm) {
            int idx = tid * 16 + (mm ^ stag);
            float2 e = sm.p2.sbs[idx];
            int kk = sm.p2.sbk[idx];
            if (e.x < b1 || (e.x == b1 && kk < k1)) { b1 = e.x; k1 = kk; }
        }
        const float th = b1 + TAU;
        int nb = 0; bool asec = false;
        float b2 = 3.4e38f; int k2 = 0x7fffffff;
        #pragma unroll 1
        for (int mm = 0; mm < 16; ++mm) {
            int idx = tid * 16 + (mm ^ stag);
            float2 e = sm.p2.sbs[idx];
            int kk = sm.p2.sbk[idx];
            nb  += (e.x <= th) ? 1 : 0;
            asec = asec || (e.y <= th);
            if (kk != k1 && (e.x < b2 || (e.x == b2 && kk < k2))) { b2 = e.x; k2 = kk; }
        }
        sm.p2.sbest[tid] = k1;
        idxout[row0 + tid] = (float)k1;
        const int row = (int)(row0 + tid);
        if (asec || nb > 2) {
            int s2 = atomicAdd(cnt_full, 1);
            flist[s2] = row;
        } else if (nb == 2) {
            int slot = atomicAdd(cnt_pair, 1);
            if (slot < CAPP) { plist[2 * slot] = row; plist[2 * slot + 1] = k2; }
            else { int s2 = atomicAdd(cnt_full, 1); flist[s2] = row; }
        }
    }
    __syncthreads();

    float4* zq4 = reinterpret_cast<float4*>(zq);
    for (int i = tid; i < 128 * 32; i += 256) {
        int r = i >> 5, c4 = i & 31;
        zq4[row0 * 32 + i] = W4[(size_t)sm.p2.sbest[r] * 32 + c4];
    }
#undef STAGE_TILE
}

// ---- stage 2 (fused): pair arbitration (thread/row) + full rescan (wave/row) ----
__global__ __launch_bounds__(256, 4) void vq_fix(
    const float* __restrict__ x, const float* __restrict__ W,
    const float* __restrict__ Wt, const float* __restrict__ swsq_ws,
    float* __restrict__ zq, float* __restrict__ idxout,
    const int* __restrict__ cnt_pair, const int* __restrict__ plist,
    const int* __restrict__ cnt_full, const int* __restrict__ flist)
{
#pragma clang fp contract(off)
    const float4* W4 = reinterpret_cast<const float4*>(W);
    float4* zq4 = reinterpret_cast<float4*>(zq);

    {   // phase A: 2-candidate numpy-exact arbitration
        int n = *cnt_pair; if (n > CAPP) n = CAPP;
        const int gsz = gridDim.x * 256;
        for (int i = blockIdx.x * 256 + threadIdx.x; i < n; i += gsz) {
            const int row = plist[2 * i];
            const int k2  = plist[2 * i + 1];
            const int k1  = (int)idxout[row];
            const float4* xr4 = reinterpret_cast<const float4*>(x + (size_t)row * EDIM);
            float4 A = xr4[0], B = xr4[1];
            float r0 = A.x*A.x, r1 = A.y*A.y, r2 = A.z*A.z, r3 = A.w*A.w;
            float r4 = B.x*B.x, r5 = B.y*B.y, r6 = B.z*B.z, r7 = B.w*B.w;
            #pragma unroll
            for (int q = 2; q < 32; q += 2) {
                float4 C = xr4[q], D = xr4[q + 1];
                r0 += C.x*C.x; r1 += C.y*C.y; r2 += C.z*C.z; r3 += C.w*C.w;
                r4 += D.x*D.x; r5 += D.y*D.y; r6 += D.z*D.z; r7 += D.w*D.w;
            }
            float xxv = ((r0 + r1) + (r2 + r3)) + ((r4 + r5) + (r6 + r7));
            const float* xr = x + (size_t)row * EDIM;
            const float* w1 = W + (size_t)k1 * EDIM;
            const float* w2 = W + (size_t)k2 * EDIM;
            float dot1 = 0.f, dot2 = 0.f;
            #pragma unroll 4
            for (int j = 0; j < EDIM; ++j) {
                float a = xr[j];
                dot1 = fmaf(a, w1[j], dot1);
                dot2 = fmaf(a, w2[j], dot2);
            }
            float d1 = (xxv + swsq_ws[k1]) - (dot1 + dot1);
            float d2 = (xxv + swsq_ws[k2]) - (dot2 + dot2);
            int kw = (d2 < d1 || (d2 == d1 && k2 < k1)) ? k2 : k1;   // first-index
            if (kw != k1) {
                idxout[row] = (float)kw;
                const float4* wr = W4 + (size_t)kw * 32;
                float4* zr = zq4 + (size_t)row * 32;
                #pragma unroll
                for (int q = 0; q < 32; ++q) zr[q] = wr[q];
            }
        }
    }

    {   // phase B: full numpy-exact rescan (disjoint row set)
        const int nf = *cnt_full;
        const int lane = threadIdx.x & 63;
        const int nw = gridDim.x * 4;
        const float4* Wt4 = reinterpret_cast<const float4*>(Wt);
        for (int i = blockIdx.x * 4 + (threadIdx.x >> 6); i < nf; i += nw) {
            const long long row = flist[i];
            const float4* xr4 = reinterpret_cast<const float4*>(x + row * EDIM);
            float xxv;
            {
                float4 A = xr4[0], B = xr4[1];
                float r0 = A.x*A.x, r1 = A.y*A.y, r2 = A.z*A.z, r3 = A.w*A.w;
                float r4 = B.x*B.x, r5 = B.y*B.y, r6 = B.z*B.z, r7 = B.w*B.w;
                #pragma unroll
                for (int q = 2; q < 32; q += 2) {
                    float4 C = xr4[q], D = xr4[q + 1];
                    r0 += C.x*C.x; r1 += C.y*C.y; r2 += C.z*C.z; r3 += C.w*C.w;
                    r4 += D.x*D.x; r5 += D.y*D.y; r6 += D.z*D.z; r7 += D.w*D.w;
                }
                xxv = ((r0 + r1) + (r2 + r3)) + ((r4 + r5) + (r6 + r7));
            }
            float acc[4][4];
            #pragma unroll
            for (int c = 0; c < 4; ++c)
                #pragma unroll
                for (int e = 0; e < 4; ++e) acc[c][e] = 0.f;
            const float* xr = x + row * EDIM;
            #pragma unroll 4
            for (int j = 0; j < EDIM; ++j) {
                float a = xr[j];
                #pragma unroll
                for (int c = 0; c < 4; ++c) {
                    float4 w = Wt4[(size_t)j * 256 + c * 64 + lane];
                    acc[c][0] = fmaf(a, w.x, acc[c][0]);
                    acc[c][1] = fmaf(a, w.y, acc[c][1]);
                    acc[c][2] = fmaf(a, w.z, acc[c][2]);
                    acc[c][3] = fmaf(a, w.w, acc[c][3]);
                }
            }
            float dbest = 3.4e38f; int bkk = 0;
            #pragma unroll
            for (int c = 0; c < 4; ++c)
                #pragma unroll
                for (int e = 0; e < 4; ++e) {
                    int k = c * 256 + lane * 4 + e;
                    float t1 = xxv + swsq_ws[k];
                    float d  = t1 - (acc[c][e] + acc[c][e]);
                    if (d < dbest) { dbest = d; bkk = k; }
                }
            #pragma unroll
            for (int mk = 1; mk < 64; mk <<= 1) {
                float od = __shfl_xor(dbest, mk);
                int   ok = __shfl_xor(bkk, mk);
                if (od < dbest || (od == dbest && ok < bkk)) { dbest = od; bkk = ok; }
            }
            if (lane == 0) idxout[row] = (float)bkk;
            if (lane < 32) zq4[row * 32 + lane] = W4[(size_t)bkk * 32 + lane];
        }
    }
}

// ---- fallback: round-4 kernel (known-correct) ----
__global__ __launch_bounds__(64, 2) void vq_v4(
    const float* __restrict__ x, const float* __restrict__ W,
    float* __restrict__ zq, float* __restrict__ idxout)
{
#pragma clang fp contract(off)
    __shared__ float swsq[NE];
    __shared__ int   sbest[64];
    const int tid = threadIdx.x;
    const long long row0 = (long long)blockIdx.x * 64;
    const long long row  = row0 + tid;
    const float4* x4 = reinterpret_cast<const float4*>(x);
    const float4* W4 = reinterpret_cast<const float4*>(W);
    float4 xr[32];
    #pragma unroll
    for (int i = 0; i < 32; ++i) xr[i] = x4[row * 32 + i];
    #pragma unroll
    for (int i = 0; i < 32; ++i)
        asm volatile("" : "+v"(xr[i].x), "+v"(xr[i].y), "+v"(xr[i].z), "+v"(xr[i].w));
    for (int k = tid; k < NE; k += 64) {
        const float4* wr = W4 + (size_t)k * 32;
        float4 A = wr[0], B = wr[1];
        float r0 = A.x*A.x, r1 = A.y*A.y, r2 = A.z*A.z, r3 = A.w*A.w;
        float r4 = B.x*B.x, r5 = B.y*B.y, r6 = B.z*B.z, r7 = B.w*B.w;
        #pragma unroll
        for (int i = 2; i < 32; i += 2) {
            float4 C = wr[i], D = wr[i + 1];
            r0 += C.x*C.x; r1 += C.y*C.y; r2 += C.z*C.z; r3 += C.w*C.w;
            r4 += D.x*D.x; r5 += D.y*D.y; r6 += D.z*D.z; r7 += D.w*D.w;
        }
        swsq[k] = ((r0 + r1) + (r2 + r3)) + ((r4 + r5) + (r6 + r7));
    }
    float xxv;
    {
        float r0 = xr[0].x*xr[0].x, r1 = xr[0].y*xr[0].y;
        float r2 = xr[0].z*xr[0].z, r3 = xr[0].w*xr[0].w;
        float r4 = xr[1].x*xr[1].x, r5 = xr[1].y*xr[1].y;
        float r6 = xr[1].z*xr[1].z, r7 = xr[1].w*xr[1].w;
        #pragma unroll
        for (int i = 2; i < 32; i += 2) {
            r0 += xr[i].x*xr[i].x;     r1 += xr[i].y*xr[i].y;
            r2 += xr[i].z*xr[i].z;     r3 += xr[i].w*xr[i].w;
            r4 += xr[i+1].x*xr[i+1].x; r5 += xr[i+1].y*xr[i+1].y;
            r6 += xr[i+1].z*xr[i+1].z; r7 += xr[i+1].w*xr[i+1].w;
        }
        xxv = ((r0 + r1) + (r2 + r3)) + ((r4 + r5) + (r6 + r7));
    }
    __syncthreads();
    float dbest = 3.4e38f; int bestk = 0;
    #pragma unroll 1
    for (int k0 = 0; k0 < NE; k0 += 8) {
        float acc[8];
        #pragma unroll
        for (int c = 0; c < 8; ++c) acc[c] = 0.f;
        #pragma unroll
        for (int j4 = 0; j4 < 32; ++j4) {
            const float4 a = xr[j4];
            #pragma unroll
            for (int c = 0; c < 8; ++c) {
                float4 w = W4[(size_t)(k0 + c) * 32 + j4];
                acc[c] = fmaf(a.x, w.x, acc[c]); acc[c] = fmaf(a.y, w.y, acc[c]);
                acc[c] = fmaf(a.z, w.z, acc[c]); acc[c] = fmaf(a.w, w.w, acc[c]);
            }
        }
        #pragma unroll
        for (int c = 0; c < 8; ++c) {
            float t1 = xxv + swsq[k0 + c];
            float d  = t1 - (acc[c] + acc[c]);
            if (d < dbest) { dbest = d; bestk = k0 + c; }
        }
    }
    sbest[tid] = bestk;
    idxout[row] = (float)bestk;
    __syncthreads();
    float4* zq4 = reinterpret_cast<float4*>(zq);
    for (int i = tid; i < 64 * 32; i += 64) {
        int r = i >> 5, c4 = i & 31;
        zq4[row0 * 32 + i] = W4[(size_t)sbest[r] * 32 + c4];
    }
}

extern "C" void kernel_launch(void* const* d_in, const int* in_sizes, int n_in,
                              void* d_out, int out_size, void* d_ws, size_t ws_size,
                              hipStream_t stream) {
    (void)n_in; (void)out_size;
    const float* x = (const float*)d_in[0];
    const float* W = (const float*)d_in[1];
    const int Nrows = in_sizes[0] / EDIM;            // 262144

    float* zqp    = (float*)d_out;
    float* idxout = zqp + (size_t)Nrows * EDIM;      // indices stored as float values

    // ws: cnts(16)|whiF(256K)|wloF(256K)|swsq(4K)|Wt(512K)|plist(512K)|flist(1M)
    const size_t need = 16 + 2 * (size_t)NE * EDIM * 2 + NE * 4
                      + (size_t)NE * EDIM * 4 + (size_t)CAPP * 2 * 4
                      + (size_t)Nrows * 4;
    if (ws_size < need) {
        vq_v4<<<dim3(Nrows / 64), dim3(64), 0, stream>>>(x, W, zqp, idxout);
        return;
    }

    char* p = (char*)d_ws;
    int*            cnt_pair = (int*)p;                    // [0]
    int*            cnt_full = (int*)(p + 4);              // [1]
    unsigned short* whiF  = (unsigned short*)(p + 16);
    unsigned short* wloF  = whiF + NE * EDIM;
    float*          swsqw = (float*)(wloF + NE * EDIM);
    float*          Wt    = swsqw + NE;
    int*            plist = (int*)(Wt + NE * EDIM);        // CAPP x {row,k2}
    int*            flist = plist + CAPP * 2;              // Nrows rows

    hipMemsetAsync(d_ws, 0, 16, stream);                   // r7/r11-proven reset
    vq_prep<<<dim3(256), dim3(256), 0, stream>>>(W, whiF, wloF, Wt, swsqw);
    vq_mfma12<<<dim3(Nrows / 128), dim3(256), 0, stream>>>(x, whiF, wloF, W, swsqw,
                                                           zqp, idxout,
                                                           cnt_pair, cnt_full,
                                                           plist, flist);
    vq_fix<<<dim3(1024), dim3(256), 0, stream>>>(x, W, Wt, swsqw, zqp, idxout,
                                                 cnt_pair, plist, cnt_full, flist);
}

// Round 20
// 331.575 us; speedup vs baseline: 1.4992x; 1.4992x over previous
//
#include <hip/hip_runtime.h>

#define EDIM 128
#define NE   1024
#define TAU  5e-5f   // disagreement bound 3.36e-5 (2*ulp(128)+split err) x1.49 margin
#define CAPP 65536   // pair-list capacity (entries); overflow -> full list

typedef short v8s __attribute__((ext_vector_type(8)));
typedef float v4f __attribute__((ext_vector_type(4)));
typedef __attribute__((address_space(3))) void       lds_t;
typedef const __attribute__((address_space(1))) void gm_t;

__device__ inline unsigned bf16_rne(float f) {
    unsigned u = __float_as_uint(f);
    return (u + 0x7fffu + ((u >> 16) & 1u)) >> 16;
}
__device__ inline float bf16_tof(unsigned h) { return __uint_as_float(h << 16); }

// ---- prep: W -> fragment-ordered bf16 hi/lo (coalesced READ, 4KB-window
//      scatter write), W -> Wt (coalesced write), numpy-exact swsq ----
__global__ void vq_prep(const float* __restrict__ W,
                        unsigned short* __restrict__ whiF,
                        unsigned short* __restrict__ wloF,
                        float* __restrict__ Wt,
                        float* __restrict__ swsq_ws)
{
#pragma clang fp contract(off)
    const int t = blockIdx.x * 256 + threadIdx.x;     // 65536 threads (256 blocks)
    #pragma unroll
    for (int rep = 0; rep < 2; ++rep) {
        int i = t + rep * 65536;
        float v = W[i];                               // coalesced read
        int code = i >> 7, k = i & 127;
        int sub = code >> 4, m = code & 15;
        int ks = k >> 5, g = (k >> 3) & 3, e = k & 7;
        int o = sub * 2048 + ks * 512 + (g * 16 + m) * 8 + e;
        unsigned h = bf16_rne(v);
        whiF[o] = (unsigned short)h;                  // scatter within 4KB window
        wloF[o] = (unsigned short)bf16_rne(v - bf16_tof(h));
        int o2 = t + rep * 65536;
        Wt[o2] = W[(o2 & 1023) * EDIM + (o2 >> 10)];  // coalesced write, L2 read
    }
    if (t < NE) {   // numpy pairwise 8-acc pattern (validated rounds 2-19)
        const float4* wr = reinterpret_cast<const float4*>(W) + (size_t)t * 32;
        float4 A = wr[0], B = wr[1];
        float r0 = A.x*A.x, r1 = A.y*A.y, r2 = A.z*A.z, r3 = A.w*A.w;
        float r4 = B.x*B.x, r5 = B.y*B.y, r6 = B.z*B.z, r7 = B.w*B.w;
        #pragma unroll
        for (int i = 2; i < 32; i += 2) {
            float4 C = wr[i], D = wr[i + 1];
            r0 += C.x*C.x; r1 += C.y*C.y; r2 += C.z*C.z; r3 += C.w*C.w;
            r4 += D.x*D.x; r5 += D.y*D.y; r6 += D.z*D.z; r7 += D.w*D.w;
        }
        swsq_ws[t] = ((r0 + r1) + (r2 + r3)) + ((r4 + r5) + (r6 + r7));
    }
}

union SMem {
    struct { unsigned short ring[3][2][4096]; float snwk2h[NE]; } p1;  // 52 KB
    struct { float4 scan[2048]; int sbest[128]; } p2;                  // 32.5 KB
};

// ---- stage 1: r15/r17's vq_mfma9 (215 us measured, validated) ----
__global__ __launch_bounds__(256, 3) void vq_mfma9(
    const float* __restrict__ x,
    const unsigned short* __restrict__ whiF, const unsigned short* __restrict__ wloF,
    const float* __restrict__ W, const float* __restrict__ swsq_ws,
    float* __restrict__ zq, float* __restrict__ idxout,
    int* __restrict__ cnt_pair, int* __restrict__ cnt_full,
    int* __restrict__ plist, int* __restrict__ flist)
{
    __shared__ SMem sm;

    const int tid = threadIdx.x;
    const int wid = tid >> 6;
    const int l   = tid & 63;
    const int m   = l & 15;          // B-code / C-col
    const int g   = l >> 4;          // k-group; C rows g*4+r

    const long long row0 = (long long)blockIdx.x * 128;
    const float4* x4 = reinterpret_cast<const float4*>(x);
    const float4* W4 = reinterpret_cast<const float4*>(W);

#define STAGE_TILE(T, B) do {                                                          \
    __builtin_amdgcn_global_load_lds((gm_t*)(whiF + (size_t)(T) * 4096 + tid * 8),     \
        (lds_t*)&sm.p1.ring[B][0][tid * 8], 16, 0, 0);                                 \
    __builtin_amdgcn_global_load_lds((gm_t*)(whiF + (size_t)(T) * 4096 + 2048 + tid * 8), \
        (lds_t*)&sm.p1.ring[B][0][2048 + tid * 8], 16, 0, 0);                          \
    __builtin_amdgcn_global_load_lds((gm_t*)(wloF + (size_t)(T) * 4096 + tid * 8),     \
        (lds_t*)&sm.p1.ring[B][1][tid * 8], 16, 0, 0);                                 \
    __builtin_amdgcn_global_load_lds((gm_t*)(wloF + (size_t)(T) * 4096 + 2048 + tid * 8), \
        (lds_t*)&sm.p1.ring[B][1][2048 + tid * 8], 16, 0, 0);                          \
} while (0)

    // prologue: issue tiles 0,1
    STAGE_TILE(0, 0);
    STAGE_TILE(1, 1);

    {   // stage -wk2/2 into LDS
        float4 v = reinterpret_cast<const float4*>(swsq_ws)[tid];
        v.x *= -0.5f; v.y *= -0.5f; v.z *= -0.5f; v.w *= -0.5f;
        reinterpret_cast<float4*>(sm.p1.snwk2h)[tid] = v;
    }

    // A-fragments for 2 row-subtiles: rows row0+wid*32+m and +16
    const long long rA0 = row0 + wid * 32 + m;
    const long long rA1 = rA0 + 16;
    v8s a0h[4], a0l[4], a1h[4], a1l[4];
    #pragma unroll
    for (int ks = 0; ks < 4; ++ks) {
        float4 p0 = x4[rA0 * 32 + ks * 8 + g * 2];
        float4 p1 = x4[rA0 * 32 + ks * 8 + g * 2 + 1];
        float4 q0 = x4[rA1 * 32 + ks * 8 + g * 2];
        float4 q1 = x4[rA1 * 32 + ks * 8 + g * 2 + 1];
        float vp[8] = {p0.x,p0.y,p0.z,p0.w,p1.x,p1.y,p1.z,p1.w};
        float vq[8] = {q0.x,q0.y,q0.z,q0.w,q1.x,q1.y,q1.z,q1.w};
        #pragma unroll
        for (int e = 0; e < 8; ++e) {
            unsigned h0 = bf16_rne(vp[e]);
            a0h[ks][e] = (short)h0;
            a0l[ks][e] = (short)bf16_rne(vp[e] - bf16_tof(h0));
            unsigned h1 = bf16_rne(vq[e]);
            a1h[ks][e] = (short)h1;
            a1l[ks][e] = (short)bf16_rne(vq[e] - bf16_tof(h1));
        }
    }
    __syncthreads();   // drains prologue staging (tiles 0,1) + snwk2h

    float best[8], sec[8]; int bk[8];
    #pragma unroll
    for (int r = 0; r < 8; ++r) { best[r] = -3.4e38f; sec[r] = -3.4e38f; bk[r] = 0; }

    int bcur = 0;                       // t % 3
    #pragma unroll 1
    for (int t = 0; t < 32; ++t) {
        if (t + 1 < 32) asm volatile("s_waitcnt vmcnt(4)" ::: "memory");
        else            asm volatile("s_waitcnt vmcnt(0)" ::: "memory");
        __builtin_amdgcn_s_barrier();

        if (t + 2 < 32) {
            int bnext = bcur + 2; if (bnext >= 3) bnext -= 3;
            STAGE_TILE(t + 2, bnext);
        }

        const unsigned short* bh_base = &sm.p1.ring[bcur][0][l * 8];
        const unsigned short* bl_base = &sm.p1.ring[bcur][1][l * 8];

        #pragma unroll
        for (int half = 0; half < 2; ++half) {   // k ascending: half0 then half1
            const int k = t * 32 + half * 16 + m;
            const int hb = half * 2048;
            v8s bh0 = *(const v8s*)(bh_base + hb);
            v8s bh1 = *(const v8s*)(bh_base + hb + 512);
            v8s bh2 = *(const v8s*)(bh_base + hb + 1024);
            v8s bh3 = *(const v8s*)(bh_base + hb + 1536);
            v8s bl0 = *(const v8s*)(bl_base + hb);
            v8s bl1 = *(const v8s*)(bl_base + hb + 512);
            v8s bl2 = *(const v8s*)(bl_base + hb + 1024);
            v8s bl3 = *(const v8s*)(bl_base + hb + 1536);

            const float h = sm.p1.snwk2h[k];     // -wk2/2, C-init (broadcast)
            v4f acc0 = {h, h, h, h};
            v4f acc1 = {h, h, h, h};
            __builtin_amdgcn_s_setprio(1);
            acc0 = __builtin_amdgcn_mfma_f32_16x16x32_bf16(a0h[0], bh0, acc0, 0, 0, 0);
            acc0 = __builtin_amdgcn_mfma_f32_16x16x32_bf16(a0l[0], bh0, acc0, 0, 0, 0);
            acc0 = __builtin_amdgcn_mfma_f32_16x16x32_bf16(a0h[0], bl0, acc0, 0, 0, 0);
            acc1 = __builtin_amdgcn_mfma_f32_16x16x32_bf16(a1h[0], bh0, acc1, 0, 0, 0);
            acc1 = __builtin_amdgcn_mfma_f32_16x16x32_bf16(a1l[0], bh0, acc1, 0, 0, 0);
            acc1 = __builtin_amdgcn_mfma_f32_16x16x32_bf16(a1h[0], bl0, acc1, 0, 0, 0);
            acc0 = __builtin_amdgcn_mfma_f32_16x16x32_bf16(a0h[1], bh1, acc0, 0, 0, 0);
            acc0 = __builtin_amdgcn_mfma_f32_16x16x32_bf16(a0l[1], bh1, acc0, 0, 0, 0);
            acc0 = __builtin_amdgcn_mfma_f32_16x16x32_bf16(a0h[1], bl1, acc0, 0, 0, 0);
            acc1 = __builtin_amdgcn_mfma_f32_16x16x32_bf16(a1h[1], bh1, acc1, 0, 0, 0);
            acc1 = __builtin_amdgcn_mfma_f32_16x16x32_bf16(a1l[1], bh1, acc1, 0, 0, 0);
            acc1 = __builtin_amdgcn_mfma_f32_16x16x32_bf16(a1h[1], bl1, acc1, 0, 0, 0);
            acc0 = __builtin_amdgcn_mfma_f32_16x16x32_bf16(a0h[2], bh2, acc0, 0, 0, 0);
            acc0 = __builtin_amdgcn_mfma_f32_16x16x32_bf16(a0l[2], bh2, acc0, 0, 0, 0);
            acc0 = __builtin_amdgcn_mfma_f32_16x16x32_bf16(a0h[2], bl2, acc0, 0, 0, 0);
            acc1 = __builtin_amdgcn_mfma_f32_16x16x32_bf16(a1h[2], bh2, acc1, 0, 0, 0);
            acc1 = __builtin_amdgcn_mfma_f32_16x16x32_bf16(a1l[2], bh2, acc1, 0, 0, 0);
            acc1 = __builtin_amdgcn_mfma_f32_16x16x32_bf16(a1h[2], bl2, acc1, 0, 0, 0);
            acc0 = __builtin_amdgcn_mfma_f32_16x16x32_bf16(a0h[3], bh3, acc0, 0, 0, 0);
            acc0 = __builtin_amdgcn_mfma_f32_16x16x32_bf16(a0l[3], bh3, acc0, 0, 0, 0);
            acc0 = __builtin_amdgcn_mfma_f32_16x16x32_bf16(a0h[3], bl3, acc0, 0, 0, 0);
            acc1 = __builtin_amdgcn_mfma_f32_16x16x32_bf16(a1h[3], bh3, acc1, 0, 0, 0);
            acc1 = __builtin_amdgcn_mfma_f32_16x16x32_bf16(a1l[3], bh3, acc1, 0, 0, 0);
            acc1 = __builtin_amdgcn_mfma_f32_16x16x32_bf16(a1h[3], bl3, acc1, 0, 0, 0);
            __builtin_amdgcn_s_setprio(0);

            #pragma unroll
            for (int r = 0; r < 4; ++r) {
                float b0 = best[r];
                float a0r = acc0[r];
                sec[r]  = __builtin_amdgcn_fmed3f(a0r, b0, sec[r]);   // 2nd-largest
                bk[r]   = (a0r > b0) ? k : bk[r];
                best[r] = fmaxf(b0, a0r);
                float b1 = best[4 + r];
                float a1r = acc1[r];
                sec[4+r]  = __builtin_amdgcn_fmed3f(a1r, b1, sec[4+r]);
                bk[4+r]   = (a1r > b1) ? k : bk[4+r];
                best[4+r] = fmaxf(b1, a1r);
            }
        }

        bcur = (bcur == 2) ? 0 : bcur + 1;
    }
    __syncthreads();   // ring reads done before scan overwrites (union)

    // ---- dump per-lane top-2 (converted back to s = -2a) + census ----
    #pragma unroll
    for (int r = 0; r < 8; ++r) {
        int rowL = wid * 32 + ((r >> 2) << 4) + (g << 2) + (r & 3);
        float4 e;
        e.x = -2.f * best[r]; e.y = -2.f * sec[r];
        e.z = __int_as_float(bk[r]); e.w = 0.f;
        sm.p2.scan[rowL * 16 + m] = e;
    }
    __syncthreads();

    if (tid < 128) {
        const int stag = tid & 7;                 // slot stagger (order-independent)
        float b1 = 3.4e38f; int k1 = 0x7fffffff;
        #pragma unroll 1
        for (int mm = 0; mm < 16; ++mm) {
            float4 e = sm.p2.scan[tid * 16 + (mm ^ stag)];
            int kk = __float_as_int(e.z);
            if (e.x < b1 || (e.x == b1 && kk < k1)) { b1 = e.x; k1 = kk; }
        }
        const float th = b1 + TAU;
        int nb = 0; bool asec = false;
        float b2 = 3.4e38f; int k2 = 0x7fffffff;
        #pragma unroll 1
        for (int mm = 0; mm < 16; ++mm) {
            float4 e = sm.p2.scan[tid * 16 + (mm ^ stag)];
            int kk = __float_as_int(e.z);
            nb  += (e.x <= th) ? 1 : 0;
            asec = asec || (e.y <= th);
            if (kk != k1 && (e.x < b2 || (e.x == b2 && kk < k2))) { b2 = e.x; k2 = kk; }
        }
        sm.p2.sbest[tid] = k1;
        idxout[row0 + tid] = (float)k1;
        const int row = (int)(row0 + tid);
        if (asec || nb > 2) {
            int s2 = atomicAdd(cnt_full, 1);
            flist[s2] = row;
        } else if (nb == 2) {
            int slot = atomicAdd(cnt_pair, 1);
            if (slot < CAPP) { plist[2 * slot] = row; plist[2 * slot + 1] = k2; }
            else { int s2 = atomicAdd(cnt_full, 1); flist[s2] = row; }
        }
    }
    __syncthreads();

    float4* zq4 = reinterpret_cast<float4*>(zq);
    for (int i = tid; i < 128 * 32; i += 256) {
        int r = i >> 5, c4 = i & 31;
        zq4[row0 * 32 + i] = W4[(size_t)sm.p2.sbest[r] * 32 + c4];
    }
#undef STAGE_TILE
}

// ---- stage 2 (fused): pair arbitration (thread/row) + full rescan (wave/row) ----
__global__ __launch_bounds__(256, 4) void vq_fix(
    const float* __restrict__ x, const float* __restrict__ W,
    const float* __restrict__ Wt, const float* __restrict__ swsq_ws,
    float* __restrict__ zq, float* __restrict__ idxout,
    const int* __restrict__ cnt_pair, const int* __restrict__ plist,
    const int* __restrict__ cnt_full, const int* __restrict__ flist)
{
#pragma clang fp contract(off)
    const float4* W4 = reinterpret_cast<const float4*>(W);
    float4* zq4 = reinterpret_cast<float4*>(zq);

    {   // phase A: 2-candidate numpy-exact arbitration
        int n = *cnt_pair; if (n > CAPP) n = CAPP;
        const int gsz = gridDim.x * 256;
        for (int i = blockIdx.x * 256 + threadIdx.x; i < n; i += gsz) {
            const int row = plist[2 * i];
            const int k2  = plist[2 * i + 1];
            const int k1  = (int)idxout[row];
            const float4* xr4 = reinterpret_cast<const float4*>(x + (size_t)row * EDIM);
            float4 A = xr4[0], B = xr4[1];
            float r0 = A.x*A.x, r1 = A.y*A.y, r2 = A.z*A.z, r3 = A.w*A.w;
            float r4 = B.x*B.x, r5 = B.y*B.y, r6 = B.z*B.z, r7 = B.w*B.w;
            #pragma unroll
            for (int q = 2; q < 32; q += 2) {
                float4 C = xr4[q], D = xr4[q + 1];
                r0 += C.x*C.x; r1 += C.y*C.y; r2 += C.z*C.z; r3 += C.w*C.w;
                r4 += D.x*D.x; r5 += D.y*D.y; r6 += D.z*D.z; r7 += D.w*D.w;
            }
            float xxv = ((r0 + r1) + (r2 + r3)) + ((r4 + r5) + (r6 + r7));
            const float* xr = x + (size_t)row * EDIM;
            const float* w1 = W + (size_t)k1 * EDIM;
            const float* w2 = W + (size_t)k2 * EDIM;
            float dot1 = 0.f, dot2 = 0.f;
            #pragma unroll 4
            for (int j = 0; j < EDIM; ++j) {
                float a = xr[j];
                dot1 = fmaf(a, w1[j], dot1);
                dot2 = fmaf(a, w2[j], dot2);
            }
            float d1 = (xxv + swsq_ws[k1]) - (dot1 + dot1);
            float d2 = (xxv + swsq_ws[k2]) - (dot2 + dot2);
            int kw = (d2 < d1 || (d2 == d1 && k2 < k1)) ? k2 : k1;   // first-index
            if (kw != k1) {
                idxout[row] = (float)kw;
                const float4* wr = W4 + (size_t)kw * 32;
                float4* zr = zq4 + (size_t)row * 32;
                #pragma unroll
                for (int q = 0; q < 32; ++q) zr[q] = wr[q];
            }
        }
    }

    {   // phase B: full numpy-exact rescan (disjoint row set)
        const int nf = *cnt_full;
        const int lane = threadIdx.x & 63;
        const int nw = gridDim.x * 4;
        const float4* Wt4 = reinterpret_cast<const float4*>(Wt);
        for (int i = blockIdx.x * 4 + (threadIdx.x >> 6); i < nf; i += nw) {
            const long long row = flist[i];
            const float4* xr4 = reinterpret_cast<const float4*>(x + row * EDIM);
            float xxv;
            {
                float4 A = xr4[0], B = xr4[1];
                float r0 = A.x*A.x, r1 = A.y*A.y, r2 = A.z*A.z, r3 = A.w*A.w;
                float r4 = B.x*B.x, r5 = B.y*B.y, r6 = B.z*B.z, r7 = B.w*B.w;
                #pragma unroll
                for (int q = 2; q < 32; q += 2) {
                    float4 C = xr4[q], D = xr4[q + 1];
                    r0 += C.x*C.x; r1 += C.y*C.y; r2 += C.z*C.z; r3 += C.w*C.w;
                    r4 += D.x*D.x; r5 += D.y*D.y; r6 += D.z*D.z; r7 += D.w*D.w;
                }
                xxv = ((r0 + r1) + (r2 + r3)) + ((r4 + r5) + (r6 + r7));
            }
            float acc[4][4];
            #pragma unroll
            for (int c = 0; c < 4; ++c)
                #pragma unroll
                for (int e = 0; e < 4; ++e) acc[c][e] = 0.f;
            const float* xr = x + row * EDIM;
            #pragma unroll 4
            for (int j = 0; j < EDIM; ++j) {
                float a = xr[j];
                #pragma unroll
                for (int c = 0; c < 4; ++c) {
                    float4 w = Wt4[(size_t)j * 256 + c * 64 + lane];
                    acc[c][0] = fmaf(a, w.x, acc[c][0]);
                    acc[c][1] = fmaf(a, w.y, acc[c][1]);
                    acc[c][2] = fmaf(a, w.z, acc[c][2]);
                    acc[c][3] = fmaf(a, w.w, acc[c][3]);
                }
            }
            float dbest = 3.4e38f; int bkk = 0;
            #pragma unroll
            for (int c = 0; c < 4; ++c)
                #pragma unroll
                for (int e = 0; e < 4; ++e) {
                    int k = c * 256 + lane * 4 + e;
                    float t1 = xxv + swsq_ws[k];
                    float d  = t1 - (acc[c][e] + acc[c][e]);
                    if (d < dbest) { dbest = d; bkk = k; }
                }
            #pragma unroll
            for (int mk = 1; mk < 64; mk <<= 1) {
                float od = __shfl_xor(dbest, mk);
                int   ok = __shfl_xor(bkk, mk);
                if (od < dbest || (od == dbest && ok < bkk)) { dbest = od; bkk = ok; }
            }
            if (lane == 0) idxout[row] = (float)bkk;
            if (lane < 32) zq4[row * 32 + lane] = W4[(size_t)bkk * 32 + lane];
        }
    }
}

// ---- fallback: round-4 kernel (known-correct) ----
__global__ __launch_bounds__(64, 2) void vq_v4(
    const float* __restrict__ x, const float* __restrict__ W,
    float* __restrict__ zq, float* __restrict__ idxout)
{
#pragma clang fp contract(off)
    __shared__ float swsq[NE];
    __shared__ int   sbest[64];
    const int tid = threadIdx.x;
    const long long row0 = (long long)blockIdx.x * 64;
    const long long row  = row0 + tid;
    const float4* x4 = reinterpret_cast<const float4*>(x);
    const float4* W4 = reinterpret_cast<const float4*>(W);
    float4 xr[32];
    #pragma unroll
    for (int i = 0; i < 32; ++i) xr[i] = x4[row * 32 + i];
    #pragma unroll
    for (int i = 0; i < 32; ++i)
        asm volatile("" : "+v"(xr[i].x), "+v"(xr[i].y), "+v"(xr[i].z), "+v"(xr[i].w));
    for (int k = tid; k < NE; k += 64) {
        const float4* wr = W4 + (size_t)k * 32;
        float4 A = wr[0], B = wr[1];
        float r0 = A.x*A.x, r1 = A.y*A.y, r2 = A.z*A.z, r3 = A.w*A.w;
        float r4 = B.x*B.x, r5 = B.y*B.y, r6 = B.z*B.z, r7 = B.w*B.w;
        #pragma unroll
        for (int i = 2; i < 32; i += 2) {
            float4 C = wr[i], D = wr[i + 1];
            r0 += C.x*C.x; r1 += C.y*C.y; r2 += C.z*C.z; r3 += C.w*C.w;
            r4 += D.x*D.x; r5 += D.y*D.y; r6 += D.z*D.z; r7 += D.w*D.w;
        }
        swsq[k] = ((r0 + r1) + (r2 + r3)) + ((r4 + r5) + (r6 + r7));
    }
    float xxv;
    {
        float r0 = xr[0].x*xr[0].x, r1 = xr[0].y*xr[0].y;
        float r2 = xr[0].z*xr[0].z, r3 = xr[0].w*xr[0].w;
        float r4 = xr[1].x*xr[1].x, r5 = xr[1].y*xr[1].y;
        float r6 = xr[1].z*xr[1].z, r7 = xr[1].w*xr[1].w;
        #pragma unroll
        for (int i = 2; i < 32; i += 2) {
            r0 += xr[i].x*xr[i].x;     r1 += xr[i].y*xr[i].y;
            r2 += xr[i].z*xr[i].z;     r3 += xr[i].w*xr[i].w;
            r4 += xr[i+1].x*xr[i+1].x; r5 += xr[i+1].y*xr[i+1].y;
            r6 += xr[i+1].z*xr[i+1].z; r7 += xr[i+1].w*xr[i+1].w;
        }
        xxv = ((r0 + r1) + (r2 + r3)) + ((r4 + r5) + (r6 + r7));
    }
    __syncthreads();
    float dbest = 3.4e38f; int bestk = 0;
    #pragma unroll 1
    for (int k0 = 0; k0 < NE; k0 += 8) {
        float acc[8];
        #pragma unroll
        for (int c = 0; c < 8; ++c) acc[c] = 0.f;
        #pragma unroll
        for (int j4 = 0; j4 < 32; ++j4) {
            const float4 a = xr[j4];
            #pragma unroll
            for (int c = 0; c < 8; ++c) {
                float4 w = W4[(size_t)(k0 + c) * 32 + j4];
                acc[c] = fmaf(a.x, w.x, acc[c]); acc[c] = fmaf(a.y, w.y, acc[c]);
                acc[c] = fmaf(a.z, w.z, acc[c]); acc[c] = fmaf(a.w, w.w, acc[c]);
            }
        }
        #pragma unroll
        for (int c = 0; c < 8; ++c) {
            float t1 = xxv + swsq[k0 + c];
            float d  = t1 - (acc[c] + acc[c]);
            if (d < dbest) { dbest = d; bestk = k0 + c; }
        }
    }
    sbest[tid] = bestk;
    idxout[row] = (float)bestk;
    __syncthreads();
    float4* zq4 = reinterpret_cast<float4*>(zq);
    for (int i = tid; i < 64 * 32; i += 64) {
        int r = i >> 5, c4 = i & 31;
        zq4[row0 * 32 + i] = W4[(size_t)sbest[r] * 32 + c4];
    }
}

extern "C" void kernel_launch(void* const* d_in, const int* in_sizes, int n_in,
                              void* d_out, int out_size, void* d_ws, size_t ws_size,
                              hipStream_t stream) {
    (void)n_in; (void)out_size;
    const float* x = (const float*)d_in[0];
    const float* W = (const float*)d_in[1];
    const int Nrows = in_sizes[0] / EDIM;            // 262144

    float* zqp    = (float*)d_out;
    float* idxout = zqp + (size_t)Nrows * EDIM;      // indices stored as float values

    // ws: cnts(16)|whiF(256K)|wloF(256K)|swsq(4K)|Wt(512K)|plist(512K)|flist(1M)
    const size_t need = 16 + 2 * (size_t)NE * EDIM * 2 + NE * 4
                      + (size_t)NE * EDIM * 4 + (size_t)CAPP * 2 * 4
                      + (size_t)Nrows * 4;
    if (ws_size < need) {
        vq_v4<<<dim3(Nrows / 64), dim3(64), 0, stream>>>(x, W, zqp, idxout);
        return;
    }

    char* p = (char*)d_ws;
    int*            cnt_pair = (int*)p;                    // [0]
    int*            cnt_full = (int*)(p + 4);              // [1]
    unsigned short* whiF  = (unsigned short*)(p + 16);
    unsigned short* wloF  = whiF + NE * EDIM;
    float*          swsqw = (float*)(wloF + NE * EDIM);
    float*          Wt    = swsqw + NE;
    int*            plist = (int*)(Wt + NE * EDIM);        // CAPP x {row,k2}
    int*            flist = plist + CAPP * 2;              // Nrows rows

    hipMemsetAsync(d_ws, 0, 16, stream);                   // r7/r11-proven reset
    vq_prep<<<dim3(256), dim3(256), 0, stream>>>(W, whiF, wloF, Wt, swsqw);
    vq_mfma9<<<dim3(Nrows / 128), dim3(256), 0, stream>>>(x, whiF, wloF, W, swsqw,
                                                          zqp, idxout,
                                                          cnt_pair, cnt_full,
                                                          plist, flist);
    vq_fix<<<dim3(1024), dim3(256), 0, stream>>>(x, W, Wt, swsqw, zqp, idxout,
                                                 cnt_pair, plist, cnt_full, flist);
}

// Round 21
// 330.125 us; speedup vs baseline: 1.5058x; 1.0044x over previous
//
#include <hip/hip_runtime.h>

#define EDIM 128
#define NE   1024
#define TAU  5e-5f   // disagreement bound 3.36e-5 (2*ulp(128)+split err) x1.49 margin
#define CAPP 65536   // pair-list capacity (entries); overflow -> full list

typedef short v8s __attribute__((ext_vector_type(8)));
typedef float v4f __attribute__((ext_vector_type(4)));
typedef __attribute__((address_space(3))) void       lds_t;
typedef const __attribute__((address_space(1))) void gm_t;

__device__ inline unsigned bf16_rne(float f) {
    unsigned u = __float_as_uint(f);
    return (u + 0x7fffu + ((u >> 16) & 1u)) >> 16;
}
__device__ inline float bf16_tof(unsigned h) { return __uint_as_float(h << 16); }

// ---- prep: W -> fragment-ordered bf16 hi/lo, W -> Wt, numpy-exact swsq ----
__global__ void vq_prep(const float* __restrict__ W,
                        unsigned short* __restrict__ whiF,
                        unsigned short* __restrict__ wloF,
                        float* __restrict__ Wt,
                        float* __restrict__ swsq_ws)
{
#pragma clang fp contract(off)
    const int t = blockIdx.x * 256 + threadIdx.x;     // 65536 threads (256 blocks)
    #pragma unroll
    for (int rep = 0; rep < 2; ++rep) {
        int i = t + rep * 65536;
        float v = W[i];                               // coalesced read
        int code = i >> 7, k = i & 127;
        int sub = code >> 4, m = code & 15;
        int ks = k >> 5, g = (k >> 3) & 3, e = k & 7;
        int o = sub * 2048 + ks * 512 + (g * 16 + m) * 8 + e;
        unsigned h = bf16_rne(v);
        whiF[o] = (unsigned short)h;                  // scatter within 4KB window
        wloF[o] = (unsigned short)bf16_rne(v - bf16_tof(h));
        int o2 = t + rep * 65536;
        Wt[o2] = W[(o2 & 1023) * EDIM + (o2 >> 10)];  // coalesced write, L2 read
    }
    if (t < NE) {   // numpy pairwise 8-acc pattern (validated rounds 2-20)
        const float4* wr = reinterpret_cast<const float4*>(W) + (size_t)t * 32;
        float4 A = wr[0], B = wr[1];
        float r0 = A.x*A.x, r1 = A.y*A.y, r2 = A.z*A.z, r3 = A.w*A.w;
        float r4 = B.x*B.x, r5 = B.y*B.y, r6 = B.z*B.z, r7 = B.w*B.w;
        #pragma unroll
        for (int i = 2; i < 32; i += 2) {
            float4 C = wr[i], D = wr[i + 1];
            r0 += C.x*C.x; r1 += C.y*C.y; r2 += C.z*C.z; r3 += C.w*C.w;
            r4 += D.x*D.x; r5 += D.y*D.y; r6 += D.z*D.z; r7 += D.w*D.w;
        }
        swsq_ws[t] = ((r0 + r1) + (r2 + r3)) + ((r4 + r5) + (r6 + r7));
    }
}

union SMem {
    struct { unsigned short ring[3][2][4096]; float snwk2h[NE]; } p1;  // 52 KB
    struct { float4 scan[2048]; int sbest[128]; } p2;                  // 32.5 KB
};

// ---- stage 1: r15/r17/r20's vq_mfma9 (215 us measured, validated) ----
__global__ __launch_bounds__(256, 3) void vq_mfma9(
    const float* __restrict__ x,
    const unsigned short* __restrict__ whiF, const unsigned short* __restrict__ wloF,
    const float* __restrict__ W, const float* __restrict__ swsq_ws,
    float* __restrict__ zq, float* __restrict__ idxout,
    int* __restrict__ cnt_pair, int* __restrict__ cnt_full,
    int* __restrict__ plist, int* __restrict__ flist)
{
    __shared__ SMem sm;

    const int tid = threadIdx.x;
    const int wid = tid >> 6;
    const int l   = tid & 63;
    const int m   = l & 15;          // B-code / C-col
    const int g   = l >> 4;          // k-group; C rows g*4+r

    const long long row0 = (long long)blockIdx.x * 128;
    const float4* x4 = reinterpret_cast<const float4*>(x);
    const float4* W4 = reinterpret_cast<const float4*>(W);

#define STAGE_TILE(T, B) do {                                                          \
    __builtin_amdgcn_global_load_lds((gm_t*)(whiF + (size_t)(T) * 4096 + tid * 8),     \
        (lds_t*)&sm.p1.ring[B][0][tid * 8], 16, 0, 0);                                 \
    __builtin_amdgcn_global_load_lds((gm_t*)(whiF + (size_t)(T) * 4096 + 2048 + tid * 8), \
        (lds_t*)&sm.p1.ring[B][0][2048 + tid * 8], 16, 0, 0);                          \
    __builtin_amdgcn_global_load_lds((gm_t*)(wloF + (size_t)(T) * 4096 + tid * 8),     \
        (lds_t*)&sm.p1.ring[B][1][tid * 8], 16, 0, 0);                                 \
    __builtin_amdgcn_global_load_lds((gm_t*)(wloF + (size_t)(T) * 4096 + 2048 + tid * 8), \
        (lds_t*)&sm.p1.ring[B][1][2048 + tid * 8], 16, 0, 0);                          \
} while (0)

    // prologue: issue tiles 0,1
    STAGE_TILE(0, 0);
    STAGE_TILE(1, 1);

    {   // stage -wk2/2 into LDS
        float4 v = reinterpret_cast<const float4*>(swsq_ws)[tid];
        v.x *= -0.5f; v.y *= -0.5f; v.z *= -0.5f; v.w *= -0.5f;
        reinterpret_cast<float4*>(sm.p1.snwk2h)[tid] = v;
    }

    // A-fragments for 2 row-subtiles: rows row0+wid*32+m and +16
    const long long rA0 = row0 + wid * 32 + m;
    const long long rA1 = rA0 + 16;
    v8s a0h[4], a0l[4], a1h[4], a1l[4];
    #pragma unroll
    for (int ks = 0; ks < 4; ++ks) {
        float4 p0 = x4[rA0 * 32 + ks * 8 + g * 2];
        float4 p1 = x4[rA0 * 32 + ks * 8 + g * 2 + 1];
        float4 q0 = x4[rA1 * 32 + ks * 8 + g * 2];
        float4 q1 = x4[rA1 * 32 + ks * 8 + g * 2 + 1];
        float vp[8] = {p0.x,p0.y,p0.z,p0.w,p1.x,p1.y,p1.z,p1.w};
        float vq[8] = {q0.x,q0.y,q0.z,q0.w,q1.x,q1.y,q1.z,q1.w};
        #pragma unroll
        for (int e = 0; e < 8; ++e) {
            unsigned h0 = bf16_rne(vp[e]);
            a0h[ks][e] = (short)h0;
            a0l[ks][e] = (short)bf16_rne(vp[e] - bf16_tof(h0));
            unsigned h1 = bf16_rne(vq[e]);
            a1h[ks][e] = (short)h1;
            a1l[ks][e] = (short)bf16_rne(vq[e] - bf16_tof(h1));
        }
    }
    __syncthreads();   // drains prologue staging (tiles 0,1) + snwk2h

    float best[8], sec[8]; int bk[8];
    #pragma unroll
    for (int r = 0; r < 8; ++r) { best[r] = -3.4e38f; sec[r] = -3.4e38f; bk[r] = 0; }

    int bcur = 0;                       // t % 3
    #pragma unroll 1
    for (int t = 0; t < 32; ++t) {
        if (t + 1 < 32) asm volatile("s_waitcnt vmcnt(4)" ::: "memory");
        else            asm volatile("s_waitcnt vmcnt(0)" ::: "memory");
        __builtin_amdgcn_s_barrier();

        if (t + 2 < 32) {
            int bnext = bcur + 2; if (bnext >= 3) bnext -= 3;
            STAGE_TILE(t + 2, bnext);
        }

        const unsigned short* bh_base = &sm.p1.ring[bcur][0][l * 8];
        const unsigned short* bl_base = &sm.p1.ring[bcur][1][l * 8];

        #pragma unroll
        for (int half = 0; half < 2; ++half) {   // k ascending: half0 then half1
            const int k = t * 32 + half * 16 + m;
            const int hb = half * 2048;
            v8s bh0 = *(const v8s*)(bh_base + hb);
            v8s bh1 = *(const v8s*)(bh_base + hb + 512);
            v8s bh2 = *(const v8s*)(bh_base + hb + 1024);
            v8s bh3 = *(const v8s*)(bh_base + hb + 1536);
            v8s bl0 = *(const v8s*)(bl_base + hb);
            v8s bl1 = *(const v8s*)(bl_base + hb + 512);
            v8s bl2 = *(const v8s*)(bl_base + hb + 1024);
            v8s bl3 = *(const v8s*)(bl_base + hb + 1536);

            const float h = sm.p1.snwk2h[k];     // -wk2/2, C-init (broadcast)
            v4f acc0 = {h, h, h, h};
            v4f acc1 = {h, h, h, h};
            __builtin_amdgcn_s_setprio(1);
            acc0 = __builtin_amdgcn_mfma_f32_16x16x32_bf16(a0h[0], bh0, acc0, 0, 0, 0);
            acc0 = __builtin_amdgcn_mfma_f32_16x16x32_bf16(a0l[0], bh0, acc0, 0, 0, 0);
            acc0 = __builtin_amdgcn_mfma_f32_16x16x32_bf16(a0h[0], bl0, acc0, 0, 0, 0);
            acc1 = __builtin_amdgcn_mfma_f32_16x16x32_bf16(a1h[0], bh0, acc1, 0, 0, 0);
            acc1 = __builtin_amdgcn_mfma_f32_16x16x32_bf16(a1l[0], bh0, acc1, 0, 0, 0);
            acc1 = __builtin_amdgcn_mfma_f32_16x16x32_bf16(a1h[0], bl0, acc1, 0, 0, 0);
            acc0 = __builtin_amdgcn_mfma_f32_16x16x32_bf16(a0h[1], bh1, acc0, 0, 0, 0);
            acc0 = __builtin_amdgcn_mfma_f32_16x16x32_bf16(a0l[1], bh1, acc0, 0, 0, 0);
            acc0 = __builtin_amdgcn_mfma_f32_16x16x32_bf16(a0h[1], bl1, acc0, 0, 0, 0);
            acc1 = __builtin_amdgcn_mfma_f32_16x16x32_bf16(a1h[1], bh1, acc1, 0, 0, 0);
            acc1 = __builtin_amdgcn_mfma_f32_16x16x32_bf16(a1l[1], bh1, acc1, 0, 0, 0);
            acc1 = __builtin_amdgcn_mfma_f32_16x16x32_bf16(a1h[1], bl1, acc1, 0, 0, 0);
            acc0 = __builtin_amdgcn_mfma_f32_16x16x32_bf16(a0h[2], bh2, acc0, 0, 0, 0);
            acc0 = __builtin_amdgcn_mfma_f32_16x16x32_bf16(a0l[2], bh2, acc0, 0, 0, 0);
            acc0 = __builtin_amdgcn_mfma_f32_16x16x32_bf16(a0h[2], bl2, acc0, 0, 0, 0);
            acc1 = __builtin_amdgcn_mfma_f32_16x16x32_bf16(a1h[2], bh2, acc1, 0, 0, 0);
            acc1 = __builtin_amdgcn_mfma_f32_16x16x32_bf16(a1l[2], bh2, acc1, 0, 0, 0);
            acc1 = __builtin_amdgcn_mfma_f32_16x16x32_bf16(a1h[2], bl2, acc1, 0, 0, 0);
            acc0 = __builtin_amdgcn_mfma_f32_16x16x32_bf16(a0h[3], bh3, acc0, 0, 0, 0);
            acc0 = __builtin_amdgcn_mfma_f32_16x16x32_bf16(a0l[3], bh3, acc0, 0, 0, 0);
            acc0 = __builtin_amdgcn_mfma_f32_16x16x32_bf16(a0h[3], bl3, acc0, 0, 0, 0);
            acc1 = __builtin_amdgcn_mfma_f32_16x16x32_bf16(a1h[3], bh3, acc1, 0, 0, 0);
            acc1 = __builtin_amdgcn_mfma_f32_16x16x32_bf16(a1l[3], bh3, acc1, 0, 0, 0);
            acc1 = __builtin_amdgcn_mfma_f32_16x16x32_bf16(a1h[3], bl3, acc1, 0, 0, 0);
            __builtin_amdgcn_s_setprio(0);

            #pragma unroll
            for (int r = 0; r < 4; ++r) {
                float b0 = best[r];
                float a0r = acc0[r];
                sec[r]  = __builtin_amdgcn_fmed3f(a0r, b0, sec[r]);   // 2nd-largest
                bk[r]   = (a0r > b0) ? k : bk[r];
                best[r] = fmaxf(b0, a0r);
                float b1 = best[4 + r];
                float a1r = acc1[r];
                sec[4+r]  = __builtin_amdgcn_fmed3f(a1r, b1, sec[4+r]);
                bk[4+r]   = (a1r > b1) ? k : bk[4+r];
                best[4+r] = fmaxf(b1, a1r);
            }
        }

        bcur = (bcur == 2) ? 0 : bcur + 1;
    }
    __syncthreads();   // ring reads done before scan overwrites (union)

    // ---- dump per-lane top-2 (converted back to s = -2a) + census ----
    #pragma unroll
    for (int r = 0; r < 8; ++r) {
        int rowL = wid * 32 + ((r >> 2) << 4) + (g << 2) + (r & 3);
        float4 e;
        e.x = -2.f * best[r]; e.y = -2.f * sec[r];
        e.z = __int_as_float(bk[r]); e.w = 0.f;
        sm.p2.scan[rowL * 16 + m] = e;
    }
    __syncthreads();

    if (tid < 128) {
        const int stag = tid & 7;                 // slot stagger (order-independent)
        float b1 = 3.4e38f; int k1 = 0x7fffffff;
        #pragma unroll 1
        for (int mm = 0; mm < 16; ++mm) {
            float4 e = sm.p2.scan[tid * 16 + (mm ^ stag)];
            int kk = __float_as_int(e.z);
            if (e.x < b1 || (e.x == b1 && kk < k1)) { b1 = e.x; k1 = kk; }
        }
        const float th = b1 + TAU;
        int nb = 0; bool asec = false;
        float b2 = 3.4e38f; int k2 = 0x7fffffff;
        #pragma unroll 1
        for (int mm = 0; mm < 16; ++mm) {
            float4 e = sm.p2.scan[tid * 16 + (mm ^ stag)];
            int kk = __float_as_int(e.z);
            nb  += (e.x <= th) ? 1 : 0;
            asec = asec || (e.y <= th);
            if (kk != k1 && (e.x < b2 || (e.x == b2 && kk < k2))) { b2 = e.x; k2 = kk; }
        }
        sm.p2.sbest[tid] = k1;
        idxout[row0 + tid] = (float)k1;
        const int row = (int)(row0 + tid);
        if (asec || nb > 2) {
            int s2 = atomicAdd(cnt_full, 1);
            flist[s2] = row;
        } else if (nb == 2) {
            int slot = atomicAdd(cnt_pair, 1);
            if (slot < CAPP) { plist[2 * slot] = row; plist[2 * slot + 1] = k2; }
            else { int s2 = atomicAdd(cnt_full, 1); flist[s2] = row; }
        }
    }
    __syncthreads();

    float4* zq4 = reinterpret_cast<float4*>(zq);
    for (int i = tid; i < 128 * 32; i += 256) {
        int r = i >> 5, c4 = i & 31;
        zq4[row0 * 32 + i] = W4[(size_t)sm.p2.sbest[r] * 32 + c4];
    }
#undef STAGE_TILE
}

// ---- stage 2 (fused): pair arbitration + full rescan. Phase A now uses
//      float4 loads with in-order unpack (fmaf sequence bit-identical). ----
__global__ __launch_bounds__(256, 4) void vq_fix(
    const float* __restrict__ x, const float* __restrict__ W,
    const float* __restrict__ Wt, const float* __restrict__ swsq_ws,
    float* __restrict__ zq, float* __restrict__ idxout,
    const int* __restrict__ cnt_pair, const int* __restrict__ plist,
    const int* __restrict__ cnt_full, const int* __restrict__ flist)
{
#pragma clang fp contract(off)
    const float4* W4 = reinterpret_cast<const float4*>(W);
    float4* zq4 = reinterpret_cast<float4*>(zq);

    {   // phase A: 2-candidate numpy-exact arbitration (vectorized loads)
        int n = *cnt_pair; if (n > CAPP) n = CAPP;
        const int gsz = gridDim.x * 256;
        for (int i = blockIdx.x * 256 + threadIdx.x; i < n; i += gsz) {
            const int row = plist[2 * i];
            const int k2  = plist[2 * i + 1];
            const int k1  = (int)idxout[row];
            const float4* xr4 = reinterpret_cast<const float4*>(x + (size_t)row * EDIM);
            const float4* w14 = W4 + (size_t)k1 * 32;
            const float4* w24 = W4 + (size_t)k2 * 32;
            // xx: numpy pairwise 8-acc
            float4 A = xr4[0], B = xr4[1];
            float r0 = A.x*A.x, r1 = A.y*A.y, r2 = A.z*A.z, r3 = A.w*A.w;
            float r4 = B.x*B.x, r5 = B.y*B.y, r6 = B.z*B.z, r7 = B.w*B.w;
            #pragma unroll
            for (int q = 2; q < 32; q += 2) {
                float4 C = xr4[q], D = xr4[q + 1];
                r0 += C.x*C.x; r1 += C.y*C.y; r2 += C.z*C.z; r3 += C.w*C.w;
                r4 += D.x*D.x; r5 += D.y*D.y; r6 += D.z*D.z; r7 += D.w*D.w;
            }
            float xxv = ((r0 + r1) + (r2 + r3)) + ((r4 + r5) + (r6 + r7));
            // sequential-j fmaf chains, float4 loads, in-order x/y/z/w unpack
            float dot1 = 0.f, dot2 = 0.f;
            #pragma unroll 4
            for (int j4 = 0; j4 < 32; ++j4) {
                float4 a = xr4[j4];
                float4 u = w14[j4];
                float4 v = w24[j4];
                dot1 = fmaf(a.x, u.x, dot1); dot1 = fmaf(a.y, u.y, dot1);
                dot1 = fmaf(a.z, u.z, dot1); dot1 = fmaf(a.w, u.w, dot1);
                dot2 = fmaf(a.x, v.x, dot2); dot2 = fmaf(a.y, v.y, dot2);
                dot2 = fmaf(a.z, v.z, dot2); dot2 = fmaf(a.w, v.w, dot2);
            }
            float d1 = (xxv + swsq_ws[k1]) - (dot1 + dot1);
            float d2 = (xxv + swsq_ws[k2]) - (dot2 + dot2);
            int kw = (d2 < d1 || (d2 == d1 && k2 < k1)) ? k2 : k1;   // first-index
            if (kw != k1) {
                idxout[row] = (float)kw;
                const float4* wr = W4 + (size_t)kw * 32;
                float4* zr = zq4 + (size_t)row * 32;
                #pragma unroll
                for (int q = 0; q < 32; ++q) zr[q] = wr[q];
            }
        }
    }

    {   // phase B: full numpy-exact rescan (disjoint row set)
        const int nf = *cnt_full;
        const int lane = threadIdx.x & 63;
        const int nw = gridDim.x * 4;
        const float4* Wt4 = reinterpret_cast<const float4*>(Wt);
        for (int i = blockIdx.x * 4 + (threadIdx.x >> 6); i < nf; i += nw) {
            const long long row = flist[i];
            const float4* xr4 = reinterpret_cast<const float4*>(x + row * EDIM);
            float xxv;
            {
                float4 A = xr4[0], B = xr4[1];
                float r0 = A.x*A.x, r1 = A.y*A.y, r2 = A.z*A.z, r3 = A.w*A.w;
                float r4 = B.x*B.x, r5 = B.y*B.y, r6 = B.z*B.z, r7 = B.w*B.w;
                #pragma unroll
                for (int q = 2; q < 32; q += 2) {
                    float4 C = xr4[q], D = xr4[q + 1];
                    r0 += C.x*C.x; r1 += C.y*C.y; r2 += C.z*C.z; r3 += C.w*C.w;
                    r4 += D.x*D.x; r5 += D.y*D.y; r6 += D.z*D.z; r7 += D.w*D.w;
                }
                xxv = ((r0 + r1) + (r2 + r3)) + ((r4 + r5) + (r6 + r7));
            }
            float acc[4][4];
            #pragma unroll
            for (int c = 0; c < 4; ++c)
                #pragma unroll
                for (int e = 0; e < 4; ++e) acc[c][e] = 0.f;
            const float* xr = x + row * EDIM;
            #pragma unroll 4
            for (int j = 0; j < EDIM; ++j) {
                float a = xr[j];
                #pragma unroll
                for (int c = 0; c < 4; ++c) {
                    float4 w = Wt4[(size_t)j * 256 + c * 64 + lane];
                    acc[c][0] = fmaf(a, w.x, acc[c][0]);
                    acc[c][1] = fmaf(a, w.y, acc[c][1]);
                    acc[c][2] = fmaf(a, w.z, acc[c][2]);
                    acc[c][3] = fmaf(a, w.w, acc[c][3]);
                }
            }
            float dbest = 3.4e38f; int bkk = 0;
            #pragma unroll
            for (int c = 0; c < 4; ++c)
                #pragma unroll
                for (int e = 0; e < 4; ++e) {
                    int k = c * 256 + lane * 4 + e;
                    float t1 = xxv + swsq_ws[k];
                    float d  = t1 - (acc[c][e] + acc[c][e]);
                    if (d < dbest) { dbest = d; bkk = k; }
                }
            #pragma unroll
            for (int mk = 1; mk < 64; mk <<= 1) {
                float od = __shfl_xor(dbest, mk);
                int   ok = __shfl_xor(bkk, mk);
                if (od < dbest || (od == dbest && ok < bkk)) { dbest = od; bkk = ok; }
            }
            if (lane == 0) idxout[row] = (float)bkk;
            if (lane < 32) zq4[row * 32 + lane] = W4[(size_t)bkk * 32 + lane];
        }
    }
}

// ---- fallback: round-4 kernel (known-correct) ----
__global__ __launch_bounds__(64, 2) void vq_v4(
    const float* __restrict__ x, const float* __restrict__ W,
    float* __restrict__ zq, float* __restrict__ idxout)
{
#pragma clang fp contract(off)
    __shared__ float swsq[NE];
    __shared__ int   sbest[64];
    const int tid = threadIdx.x;
    const long long row0 = (long long)blockIdx.x * 64;
    const long long row  = row0 + tid;
    const float4* x4 = reinterpret_cast<const float4*>(x);
    const float4* W4 = reinterpret_cast<const float4*>(W);
    float4 xr[32];
    #pragma unroll
    for (int i = 0; i < 32; ++i) xr[i] = x4[row * 32 + i];
    #pragma unroll
    for (int i = 0; i < 32; ++i)
        asm volatile("" : "+v"(xr[i].x), "+v"(xr[i].y), "+v"(xr[i].z), "+v"(xr[i].w));
    for (int k = tid; k < NE; k += 64) {
        const float4* wr = W4 + (size_t)k * 32;
        float4 A = wr[0], B = wr[1];
        float r0 = A.x*A.x, r1 = A.y*A.y, r2 = A.z*A.z, r3 = A.w*A.w;
        float r4 = B.x*B.x, r5 = B.y*B.y, r6 = B.z*B.z, r7 = B.w*B.w;
        #pragma unroll
        for (int i = 2; i < 32; i += 2) {
            float4 C = wr[i], D = wr[i + 1];
            r0 += C.x*C.x; r1 += C.y*C.y; r2 += C.z*C.z; r3 += C.w*C.w;
            r4 += D.x*D.x; r5 += D.y*D.y; r6 += D.z*D.z; r7 += D.w*D.w;
        }
        swsq[k] = ((r0 + r1) + (r2 + r3)) + ((r4 + r5) + (r6 + r7));
    }
    float xxv;
    {
        float r0 = xr[0].x*xr[0].x, r1 = xr[0].y*xr[0].y;
        float r2 = xr[0].z*xr[0].z, r3 = xr[0].w*xr[0].w;
        float r4 = xr[1].x*xr[1].x, r5 = xr[1].y*xr[1].y;
        float r6 = xr[1].z*xr[1].z, r7 = xr[1].w*xr[1].w;
        #pragma unroll
        for (int i = 2; i < 32; i += 2) {
            r0 += xr[i].x*xr[i].x;     r1 += xr[i].y*xr[i].y;
            r2 += xr[i].z*xr[i].z;     r3 += xr[i].w*xr[i].w;
            r4 += xr[i+1].x*xr[i+1].x; r5 += xr[i+1].y*xr[i+1].y;
            r6 += xr[i+1].z*xr[i+1].z; r7 += xr[i+1].w*xr[i+1].w;
        }
        xxv = ((r0 + r1) + (r2 + r3)) + ((r4 + r5) + (r6 + r7));
    }
    __syncthreads();
    float dbest = 3.4e38f; int bestk = 0;
    #pragma unroll 1
    for (int k0 = 0; k0 < NE; k0 += 8) {
        float acc[8];
        #pragma unroll
        for (int c = 0; c < 8; ++c) acc[c] = 0.f;
        #pragma unroll
        for (int j4 = 0; j4 < 32; ++j4) {
            const float4 a = xr[j4];
            #pragma unroll
            for (int c = 0; c < 8; ++c) {
                float4 w = W4[(size_t)(k0 + c) * 32 + j4];
                acc[c] = fmaf(a.x, w.x, acc[c]); acc[c] = fmaf(a.y, w.y, acc[c]);
                acc[c] = fmaf(a.z, w.z, acc[c]); acc[c] = fmaf(a.w, w.w, acc[c]);
            }
        }
        #pragma unroll
        for (int c = 0; c < 8; ++c) {
            float t1 = xxv + swsq[k0 + c];
            float d  = t1 - (acc[c] + acc[c]);
            if (d < dbest) { dbest = d; bestk = k0 + c; }
        }
    }
    sbest[tid] = bestk;
    idxout[row] = (float)bestk;
    __syncthreads();
    float4* zq4 = reinterpret_cast<float4*>(zq);
    for (int i = tid; i < 64 * 32; i += 64) {
        int r = i >> 5, c4 = i & 31;
        zq4[row0 * 32 + i] = W4[(size_t)sbest[r] * 32 + c4];
    }
}

extern "C" void kernel_launch(void* const* d_in, const int* in_sizes, int n_in,
                              void* d_out, int out_size, void* d_ws, size_t ws_size,
                              hipStream_t stream) {
    (void)n_in; (void)out_size;
    const float* x = (const float*)d_in[0];
    const float* W = (const float*)d_in[1];
    const int Nrows = in_sizes[0] / EDIM;            // 262144

    float* zqp    = (float*)d_out;
    float* idxout = zqp + (size_t)Nrows * EDIM;      // indices stored as float values

    // ws: cnts(16)|whiF(256K)|wloF(256K)|swsq(4K)|Wt(512K)|plist(512K)|flist(1M)
    const size_t need = 16 + 2 * (size_t)NE * EDIM * 2 + NE * 4
                      + (size_t)NE * EDIM * 4 + (size_t)CAPP * 2 * 4
                      + (size_t)Nrows * 4;
    if (ws_size < need) {
        vq_v4<<<dim3(Nrows / 64), dim3(64), 0, stream>>>(x, W, zqp, idxout);
        return;
    }

    char* p = (char*)d_ws;
    int*            cnt_pair = (int*)p;                    // [0]
    int*            cnt_full = (int*)(p + 4);              // [1]
    unsigned short* whiF  = (unsigned short*)(p + 16);
    unsigned short* wloF  = whiF + NE * EDIM;
    float*          swsqw = (float*)(wloF + NE * EDIM);
    float*          Wt    = swsqw + NE;
    int*            plist = (int*)(Wt + NE * EDIM);        // CAPP x {row,k2}
    int*            flist = plist + CAPP * 2;              // Nrows rows

    hipMemsetAsync(d_ws, 0, 16, stream);                   // r7/r11-proven reset
    vq_prep<<<dim3(256), dim3(256), 0, stream>>>(W, whiF, wloF, Wt, swsqw);
    vq_mfma9<<<dim3(Nrows / 128), dim3(256), 0, stream>>>(x, whiF, wloF, W, swsqw,
                                                          zqp, idxout,
                                                          cnt_pair, cnt_full,
                                                          plist, flist);
    vq_fix<<<dim3(2048), dim3(256), 0, stream>>>(x, W, Wt, swsqw, zqp, idxout,
                                                 cnt_pair, plist, cnt_full, flist);
}